// Round 10
// baseline (589.368 us; speedup 1.0000x reference)
//
#include <hip/hip_runtime.h>
#include <hip/hip_bf16.h>
#include <stdint.h>

#define BATCH  512
#define INPUT  20000
#define KPAD   20032     // INPUT padded to multiple of 64 (zero-filled tail)
#define NPADE  20224     // emb rows padded to multiple of 256 (zero-filled)
#define HIDDEN 1024
#define EMBED  512
#define NOUT   2048

typedef __attribute__((ext_vector_type(8))) __bf16 bf16x8;
typedef __attribute__((ext_vector_type(8))) unsigned short u16x8;
typedef __attribute__((ext_vector_type(4))) unsigned short u16x4;
typedef __attribute__((ext_vector_type(4))) float f32x4;

static __device__ __forceinline__ unsigned short f2bf(float f) {
  uint32_t u = __builtin_bit_cast(uint32_t, f);
  u += 0x7fffu + ((u >> 16) & 1u);          // round-to-nearest-even
  return (unsigned short)(u >> 16);
}

// async global->LDS (used by the small combiner GEMM)
static __device__ __forceinline__ void g2l16(const unsigned short* g, unsigned short* l) {
  __builtin_amdgcn_global_load_lds(
      (const __attribute__((address_space(1))) void*)g,
      (__attribute__((address_space(3))) void*)l, 16, 0, 0);
}

#define MFMA(a, b, c) __builtin_amdgcn_mfma_f32_16x16x32_bf16((a), (b), (c), 0, 0, 0)

// ======= reg-staged depth-2 double-buffered 256x256 GEMM, swizzled LDS, XCD swizzle =======
// C = A @ B^T, A:[M,K] lda, B:[N,K] ldb, bf16, K-contiguous. 8 waves (2Mx4N), wave tile 128x64.
// Depth-2 pipeline: two named register sets; set S loaded 2 tiles ahead, ds_written 1 tile
// ahead (compiler emits counted vmcnt: only the older set's loads are drained).
// LDS swizzle: write col chunk = sc8 ^ (srow&XM); read col chunk = ck ^ (lr&XM)  (involution).
// XCD swizzle: blocks sharing operand panels decode to the same XCD (hardware b%8).
// EPI 0 (Et): grid 320 (x>=79 returns); C[m,n]=bf16(lrelu(acc+bias[m])) n<Nv, 0 for Nv<=n<Nw.
// EPI 1 (fused split-K): grid 256; which selects {A0,B0}/{A1,B1} and +1024 col;
//        f32 plane at Cp + z*BATCH*NOUT.
template<int EPI, int BK, int MW>
__global__ __launch_bounds__(512, MW) void gemmT(
    const unsigned short* __restrict__ A0p, const unsigned short* __restrict__ B0p,
    const unsigned short* __restrict__ A1p, const unsigned short* __restrict__ B1p,
    int lda, int ldb,
    const float* __restrict__ bias,
    void* __restrict__ Cp, int ldc,
    int Nv, int Nw, int K, int kChunk)
{
  constexpr int CPR = BK / 8;     // 16B chunks per row
  constexpr int RPP = 512 / CPR;  // rows staged per pass
  constexpr int NP  = 256 / RPP;  // passes per 256-row panel
  constexpr int KS  = BK / 32;    // MFMA k-steps per tile
  constexpr int XM  = CPR - 1;    // swizzle mask

  __shared__ __align__(16) unsigned short AsW[2 * 256 * BK];
  __shared__ __align__(16) unsigned short BsW[2 * 256 * BK];

  // ---- XCD-aware decode (hardware XCD = blockIdx % 8) ----
  const int b = blockIdx.x;
  const int xcd = b & 7, rank = b >> 3;
  int m0, n0, z = 0, which = 0;
  if (EPI == 1) {
    // 32 groups (which,z) x 8 members (x,y); group g hosted on XCD g%8
    int g  = xcd + 8 * (rank >> 3);
    int mm = rank & 7;
    which = g >> 4; z = g & 15;
    n0 = (mm >> 1) * 256; m0 = (mm & 1) * 256;
  } else {
    // groups = x (share embb panel) x 4 y-members; x hosted on XCD x%8
    int x  = xcd + 8 * (rank >> 2);
    int mm = rank & 3;
    int nx = (Nw + 255) >> 8;
    if (x >= nx) return;
    n0 = x * 256; m0 = mm * 256;
  }
  const unsigned short* Ap = which ? A1p : A0p;
  const unsigned short* Bp = which ? B1p : B0p;

  const int k0   = z * kChunk;
  const int kend = min(K, k0 + kChunk);
  const int nt   = (kend - k0) / BK;

  const int tid = threadIdx.x;
  const int l = tid & 63, w = tid >> 6;
  const int srow = tid / CPR;
  const int sc8  = tid % CPR;
  const unsigned short* agl = Ap + (size_t)(m0 + srow) * lda + k0 + sc8 * 8;
  const unsigned short* bgl = Bp + (size_t)(n0 + srow) * ldb + k0 + sc8 * 8;
  const int swc = ((sc8 ^ (srow & XM)) << 3);   // swizzled LDS write col (elements)

  const int wr = w >> 2, wc = w & 3;
  const int lr = l & 15, lkc = l >> 4;          // fragment row lane, k-chunk lane

  f32x4 acc[8][4] = {};
  u16x8 rA[2][NP], rB[2][NP];                   // two named prefetch sets

#define LOADS(S, dk)                                                           \
  do {                                                                         \
    _Pragma("unroll")                                                          \
    for (int p = 0; p < NP; ++p) {                                             \
      rA[S][p] = *reinterpret_cast<const u16x8*>(agl + (size_t)(p * RPP) * lda + (dk)); \
      rB[S][p] = *reinterpret_cast<const u16x8*>(bgl + (size_t)(p * RPP) * ldb + (dk)); \
    }                                                                          \
  } while (0)

#define WRITES(S, BUF)                                                         \
  do {                                                                         \
    _Pragma("unroll")                                                          \
    for (int p = 0; p < NP; ++p) {                                             \
      *reinterpret_cast<u16x8*>(AsW + (BUF) * (256 * BK) + (srow + p * RPP) * BK + swc) = rA[S][p]; \
      *reinterpret_cast<u16x8*>(BsW + (BUF) * (256 * BK) + (srow + p * RPP) * BK + swc) = rB[S][p]; \
    }                                                                          \
  } while (0)

#define COMPUTE(BUF)                                                           \
  do {                                                                         \
    _Pragma("unroll")                                                          \
    for (int ks = 0; ks < KS; ++ks) {                                          \
      bf16x8 af[8], bg_[4];                                                    \
      _Pragma("unroll")                                                        \
      for (int mi = 0; mi < 8; ++mi) {                                         \
        int ck = (ks * 4 + lkc) ^ (lr & XM);                                   \
        af[mi] = *reinterpret_cast<const bf16x8*>(                             \
            AsW + (BUF) * (256 * BK) + (wr * 128 + mi * 16 + lr) * BK + ck * 8); \
      }                                                                        \
      _Pragma("unroll")                                                        \
      for (int ni = 0; ni < 4; ++ni) {                                         \
        int ck = (ks * 4 + lkc) ^ (lr & XM);                                   \
        bg_[ni] = *reinterpret_cast<const bf16x8*>(                            \
            BsW + (BUF) * (256 * BK) + (wc * 64 + ni * 16 + lr) * BK + ck * 8); \
      }                                                                        \
      __builtin_amdgcn_s_setprio(1);                                           \
      _Pragma("unroll")                                                        \
      for (int mi = 0; mi < 8; ++mi)                                           \
        _Pragma("unroll")                                                      \
        for (int ni = 0; ni < 4; ++ni)                                         \
          acc[mi][ni] = MFMA(af[mi], bg_[ni], acc[mi][ni]);                    \
      __builtin_amdgcn_s_setprio(0);                                           \
    }                                                                          \
  } while (0)

  // ---- prologue: set0 <- tile0 -> buf0 ; set1 <- tile1 ----
  LOADS(0, 0);
  WRITES(0, 0);
  if (nt > 1) LOADS(1, BK);
  __syncthreads();

  for (int t = 0; t < nt; t += 2) {
    // even tile t: compute buf0; set0 free -> load tile t+2; write set1 (tile t+1) -> buf1
    if (t + 2 < nt) LOADS(0, (t + 2) * BK);
    __builtin_amdgcn_sched_barrier(0);
    COMPUTE(0);
    if (t + 1 < nt) WRITES(1, 1);     // counted vmcnt: only set1's loads drained
    __syncthreads();
    if (t + 1 < nt) {
      // odd tile t+1: compute buf1; set1 free -> load tile t+3; write set0 (t+2) -> buf0
      if (t + 3 < nt) LOADS(1, (t + 3) * BK);
      __builtin_amdgcn_sched_barrier(0);
      COMPUTE(1);
      if (t + 2 < nt) WRITES(0, 0);
      __syncthreads();
    }
  }
#undef LOADS
#undef WRITES
#undef COMPUTE

  // C/D layout: col = lane&15, row = (lane>>4)*4 + reg  [m89/m91]
  const int rb_ = (l >> 4) * 4;
#pragma unroll
  for (int mi = 0; mi < 8; ++mi)
#pragma unroll
    for (int ni = 0; ni < 4; ++ni)
#pragma unroll
      for (int j = 0; j < 4; ++j) {
        int m = m0 + wr * 128 + mi * 16 + rb_ + j;
        int n = n0 + wc * 64 + ni * 16 + lr;
        float v = acc[mi][ni][j];
        if (EPI == 0) {
          if (n < Nw) {
            float t2 = v + bias[m];
            t2 = t2 > 0.f ? t2 : 0.01f * t2;
            reinterpret_cast<unsigned short*>(Cp)[(size_t)m * ldc + n] =
                (n < Nv) ? f2bf(t2) : (unsigned short)0;
          }
        } else {
          reinterpret_cast<float*>(Cp)[(size_t)z * (BATCH * NOUT) + (size_t)m * ldc +
                                       which * 1024 + n] = v;
        }
      }
}

// ===== 128x128-tile m97-style GEMM (combiner only) =====
template<int EPI>
__global__ __launch_bounds__(256) void gemm97(
    const unsigned short* __restrict__ A, const unsigned short* __restrict__ B,
    int lda, int ldb,
    const float* __restrict__ bias,
    void* __restrict__ Cp, int ldc, int pstride,
    int M, int N, int Nw, int K, int kChunk)
{
  __shared__ __align__(16) unsigned short As[128 * 64];
  __shared__ __align__(16) unsigned short Bs[128 * 64];

  const int z = blockIdx.z;
  const int m0 = blockIdx.y * 128, n0 = blockIdx.x * 128;
  const int k0   = z * kChunk;
  const int kend = min(K, k0 + kChunk);
  const int tid = threadIdx.x;
  const int l = tid & 63, w = tid >> 6;

  const int srow = w * 32 + (l >> 3);
  const int scol = (l & 7) * 8;
  const unsigned short* ag = A + (size_t)(m0 + srow) * lda + scol;
  const unsigned short* bg = B + (size_t)(n0 + srow) * ldb + scol;

  const int wm = (w >> 1) * 64, wn = (w & 1) * 64;
  const int lr = l & 15, lk = (l >> 4) * 8;

  f32x4 acc[4][4] = {};

  for (int kb = k0; kb < kend; kb += 64) {
#pragma unroll
    for (int j = 0; j < 4; ++j)
      g2l16(ag + (size_t)j * 8 * lda + kb, As + (w * 32 + j * 8) * 64);
#pragma unroll
    for (int j = 0; j < 4; ++j)
      g2l16(bg + (size_t)j * 8 * ldb + kb, Bs + (w * 32 + j * 8) * 64);
    __syncthreads();
#pragma unroll
    for (int ks = 0; ks < 2; ++ks) {
      bf16x8 a[4], b2[4];
#pragma unroll
      for (int i = 0; i < 4; ++i)
        a[i] = *reinterpret_cast<const bf16x8*>(&As[(wm + i * 16 + lr) * 64 + ks * 32 + lk]);
#pragma unroll
      for (int i = 0; i < 4; ++i)
        b2[i] = *reinterpret_cast<const bf16x8*>(&Bs[(wn + i * 16 + lr) * 64 + ks * 32 + lk]);
#pragma unroll
      for (int mi = 0; mi < 4; ++mi)
#pragma unroll
        for (int ni = 0; ni < 4; ++ni)
          acc[mi][ni] = MFMA(a[mi], b2[ni], acc[mi][ni]);
    }
    __syncthreads();
  }

  const int rb = (l >> 4) * 4;
#pragma unroll
  for (int mi = 0; mi < 4; ++mi) {
#pragma unroll
    for (int ni = 0; ni < 4; ++ni) {
#pragma unroll
      for (int j = 0; j < 4; ++j) {
        int m = m0 + wm + mi * 16 + rb + j;
        int n = n0 + wn + ni * 16 + lr;
        float v = acc[mi][ni][j];
        if (EPI == 0) {
          if (n < Nw) {
            float t = v + bias[m];
            t = t > 0.f ? t : 0.01f * t;
            reinterpret_cast<unsigned short*>(Cp)[(size_t)m * ldc + n] =
                (n < N) ? f2bf(t) : (unsigned short)0;
          }
        } else {
          reinterpret_cast<float*>(Cp)[(size_t)z * pstride + (size_t)m * ldc + n] = v;
        }
      }
    }
  }
}

// f32 [rows,cols] -> bf16 [rowsPad,colsPad], zero-filled padding. cols % 8 == 0.
__global__ __launch_bounds__(256) void convert_kernel(
    const float* __restrict__ src, unsigned short* __restrict__ dst,
    int rows, int cols, int rowsPad, int colsPad)
{
  const int cpc = colsPad >> 3;
  const int nchunks = rowsPad * cpc;
  for (int idx = blockIdx.x * 256 + threadIdx.x; idx < nchunks; idx += gridDim.x * 256) {
    int row = idx / cpc;
    int c0  = (idx - row * cpc) << 3;
    u16x8 v = {};
    if (row < rows && c0 < cols) {
      const float* p = src + (size_t)row * cols + c0;
      f32x4 f0 = *reinterpret_cast<const f32x4*>(p);
      f32x4 f1 = *reinterpret_cast<const f32x4*>(p + 4);
      v[0] = f2bf(f0[0]); v[1] = f2bf(f0[1]); v[2] = f2bf(f0[2]); v[3] = f2bf(f0[3]);
      v[4] = f2bf(f1[0]); v[5] = f2bf(f1[1]); v[6] = f2bf(f1[2]); v[7] = f2bf(f1[3]);
    }
    *reinterpret_cast<u16x8*>(dst + (size_t)row * colsPad + c0) = v;
  }
}

// Per-row softmax stats + bf16 casts: xb = bf16(x), wb = bf16(softmax(x)), stride KPAD.
__global__ __launch_bounds__(256) void prep_x_kernel(
    const float* __restrict__ x,
    unsigned short* __restrict__ xb,
    unsigned short* __restrict__ wb)
{
  const int r = blockIdx.x;
  const int t = threadIdx.x;
  const float* xr = x + (size_t)r * INPUT;

  float m = -3.4e38f, s = 0.f;
  for (int c = t; c < INPUT / 4; c += 256) {
    float4 v = reinterpret_cast<const float4*>(xr)[c];
    float cm = fmaxf(fmaxf(v.x, v.y), fmaxf(v.z, v.w));
    if (cm > m) { s *= __expf(m - cm); m = cm; }
    s += __expf(v.x - m) + __expf(v.y - m) + __expf(v.z - m) + __expf(v.w - m);
  }
#pragma unroll
  for (int off = 32; off > 0; off >>= 1) {
    float om = __shfl_xor(m, off);
    float os = __shfl_xor(s, off);
    float nm = fmaxf(m, om);
    s = s * __expf(m - nm) + os * __expf(om - nm);
    m = nm;
  }
  __shared__ float sm[4], ss[4];
  if ((t & 63) == 0) { sm[t >> 6] = m; ss[t >> 6] = s; }
  __syncthreads();
  float M4 = fmaxf(fmaxf(sm[0], sm[1]), fmaxf(sm[2], sm[3]));
  float S4 = ss[0] * __expf(sm[0] - M4) + ss[1] * __expf(sm[1] - M4)
           + ss[2] * __expf(sm[2] - M4) + ss[3] * __expf(sm[3] - M4);
  float inv = 1.f / S4;

  unsigned short* xbr = xb + (size_t)r * KPAD;
  unsigned short* wbr = wb + (size_t)r * KPAD;
  for (int c = t; c < KPAD / 4; c += 256) {
    u16x4 xo = {}, wo = {};
    if (c < INPUT / 4) {
      float4 v = reinterpret_cast<const float4*>(xr)[c];
      xo[0] = f2bf(v.x); xo[1] = f2bf(v.y); xo[2] = f2bf(v.z); xo[3] = f2bf(v.w);
      wo[0] = f2bf(__expf(v.x - M4) * inv);
      wo[1] = f2bf(__expf(v.y - M4) * inv);
      wo[2] = f2bf(__expf(v.z - M4) * inv);
      wo[3] = f2bf(__expf(v.w - M4) * inv);
    }
    reinterpret_cast<u16x4*>(xbr)[c] = xo;
    reinterpret_cast<u16x4*>(wbr)[c] = wo;
  }
}

// Sum S split-K planes; MODE 0: combined buffer (b_ge+lrelu on cols<1024 only, bf16 out)
//                       MODE 1: final output (b_c+lrelu on all cols, f32 out)
template<int S, int MODE>
__global__ __launch_bounds__(256) void reduce_kernel(
    const float* __restrict__ P, const float* __restrict__ bias, void* __restrict__ outp)
{
  size_t base = ((size_t)blockIdx.x * 256 + threadIdx.x) * 4;
  f32x4 s = {};
#pragma unroll
  for (int zz = 0; zz < S; ++zz)
    s += *reinterpret_cast<const f32x4*>(P + (size_t)zz * BATCH * NOUT + base);
  int n = (int)(base & (NOUT - 1));
  if (MODE == 0) {
    u16x4 o;
    if (n < 1024) {
#pragma unroll
      for (int j = 0; j < 4; ++j) {
        float v = s[j] + bias[n + j];
        v = v > 0.f ? v : 0.01f * v;
        o[j] = f2bf(v);
      }
    } else {
#pragma unroll
      for (int j = 0; j < 4; ++j) o[j] = f2bf(s[j]);
    }
    *reinterpret_cast<u16x4*>(reinterpret_cast<unsigned short*>(outp) + base) = o;
  } else {
    f32x4 o;
#pragma unroll
    for (int j = 0; j < 4; ++j) {
      float v = s[j] + bias[n + j];
      o[j] = v > 0.f ? v : 0.01f * v;
    }
    *reinterpret_cast<f32x4*>(reinterpret_cast<float*>(outp) + base) = o;
  }
}

extern "C" void kernel_launch(void* const* d_in, const int* in_sizes, int n_in,
                              void* d_out, int out_size, void* d_ws, size_t ws_size,
                              hipStream_t stream)
{
  const float* x    = (const float*)d_in[0];
  const float* emb  = (const float*)d_in[1];
  const float* W_ge = (const float*)d_in[2];
  const float* b_ge = (const float*)d_in[3];
  const float* W_em = (const float*)d_in[4];
  const float* b_em = (const float*)d_in[5];
  const float* W_c  = (const float*)d_in[6];
  const float* b_c  = (const float*)d_in[7];
  float* out = (float*)d_out;

  char* ws = (char*)d_ws;
  unsigned short* xb   = (unsigned short*)(ws);                      // 512x20032 bf16  = 20,512,768
  unsigned short* wb   = (unsigned short*)(ws + 20512768);           // 20,512,768
  unsigned short* Wgeb = (unsigned short*)(ws + 41025536);           // 1024x20032 bf16 = 41,025,536
  unsigned short* Et   = (unsigned short*)(ws + 82051072);           // 1024x20032 bf16 = 41,025,536
  unsigned short* Wcb  = (unsigned short*)(ws + 123076608);          // 2048x2048 bf16  =  8,388,608
  unsigned short* comb = (unsigned short*)(ws + 131465216);          // 512x2048 bf16   =  2,097,152
  float*          P    = (float*)(ws + 133562368);                   // 16x512x2048 f32 = 67,108,864
  // embb/Wemb alias the P region (dead before P is first written)
  unsigned short* embb = (unsigned short*)(ws + 133562368);          // 20224x512 bf16  = 20,709,376
  unsigned short* Wemb = (unsigned short*)(ws + 133562368 + 20709376); // 1024x512 bf16 =  1,048,576
  // total ws usage: ~200.7 MB

  // 1) bf16 conversions (zero-padded)
  convert_kernel<<<1024, 256, 0, stream>>>(emb,  embb, INPUT, EMBED, NPADE, EMBED);
  convert_kernel<<<256,  256, 0, stream>>>(W_em, Wemb, HIDDEN, EMBED, HIDDEN, EMBED);
  convert_kernel<<<1024, 256, 0, stream>>>(W_ge, Wgeb, HIDDEN, INPUT, HIDDEN, KPAD);
  convert_kernel<<<512,  256, 0, stream>>>(W_c,  Wcb,  NOUT, NOUT, NOUT, NOUT);

  // 2) softmax stats + bf16 casts of x (stride KPAD, zero tail)
  prep_x_kernel<<<BATCH, 256, 0, stream>>>(x, xb, wb);

  // 3) Et[h,g] = lrelu(W_em @ emb^T + b_em): M=1024, N=20000 (pad 20032), K=512
  //    BK=32 -> 64KB LDS -> 2 blocks/CU: all 316 live blocks co-resident (grid 320,
  //    x>=79 returns). XCD swizzle co-locates the 4 y-siblings sharing each embb panel.
  gemmT<0, 32, 4><<<320, 512, 0, stream>>>(
      Wemb, embb, nullptr, nullptr, EMBED, EMBED, b_em,
      Et, KPAD, INPUT, KPAD, EMBED, EMBED);

  // 4) fused split-K partials: which=0: xb @ Wgeb^T -> cols 0..1023
  //                            which=1: wb @ Et^T   -> cols 1024..2047
  //    BK=64, depth-2 prefetch; XCD swizzle co-locates each (which,z) 8-block group.
  gemmT<1, 64, 2><<<256, 512, 0, stream>>>(
      xb, Wgeb, wb, Et, KPAD, KPAD, nullptr,
      P, NOUT, 0, 0, KPAD, 1280);

  // 5) reduce 16 planes -> combined bf16 [512, 2048] (+b_ge+lrelu on first half)
  reduce_kernel<16, 0><<<(BATCH * NOUT / 4) / 256, 256, 0, stream>>>(P, b_ge, comb);

  // 6) combiner partials: comb @ Wcb^T (M=512, N=2048, K=2048, S=4)
  gemm97<1><<<dim3(16, 4, 4), 256, 0, stream>>>(
      comb, Wcb, NOUT, NOUT, nullptr,
      P, NOUT, BATCH * NOUT, BATCH, NOUT, NOUT, NOUT, 512);

  // 7) reduce 4 planes + b_c + lrelu -> f32 out [512, 2048]
  reduce_kernel<4, 1><<<(BATCH * NOUT / 4) / 256, 256, 0, stream>>>(P, b_c, out);
}

// Round 11
// 229.670 us; speedup vs baseline: 2.5661x; 2.5661x over previous
//
#include <hip/hip_runtime.h>
#include <hip/hip_bf16.h>
#include <stdint.h>

#define BATCH  512
#define INPUT  20000
#define KPAD   20032     // INPUT padded to multiple of 64 (zero-filled tail)
#define NPADE  20224     // emb rows padded to multiple of 256 (zero-filled)
#define HIDDEN 1024
#define EMBED  512
#define NOUT   2048

typedef __attribute__((ext_vector_type(8))) __bf16 bf16x8;
typedef __attribute__((ext_vector_type(8))) unsigned short u16x8;
typedef __attribute__((ext_vector_type(4))) unsigned short u16x4;
typedef __attribute__((ext_vector_type(4))) float f32x4;

static __device__ __forceinline__ unsigned short f2bf(float f) {
  uint32_t u = __builtin_bit_cast(uint32_t, f);
  u += 0x7fffu + ((u >> 16) & 1u);          // round-to-nearest-even
  return (unsigned short)(u >> 16);
}

// async global->LDS (used by the small combiner GEMM)
static __device__ __forceinline__ void g2l16(const unsigned short* g, unsigned short* l) {
  __builtin_amdgcn_global_load_lds(
      (const __attribute__((address_space(1))) void*)g,
      (__attribute__((address_space(3))) void*)l, 16, 0, 0);
}

#define MFMA(a, b, c) __builtin_amdgcn_mfma_f32_16x16x32_bf16((a), (b), (c), 0, 0, 0)

// ====== 128x256-tile, 4-wave, 2-blocks/CU, reg-staged GEMM (BK=32, 48KB LDS) ======
// C = A @ B^T, A:[M,K] lda, B:[N,K] ldb, bf16 K-contiguous.
// Waves: 1(M) x 4(N); wave tile 128x64 -> acc[8][4] (128 AGPR). 2 waves/SIMD cap
// (launch_bounds(256,2)) => unified VGPR+AGPR budget 256/lane — acc 128 + ~120 fits.
// NEVER set min-waves > 2 here: R10 showed MW=4 caps the budget at 128 and spills
// the accumulator to scratch (886 MB scratch writes, 2.4x slowdown).
// Per K-tile: LOADT next tile -> named regs (issue-early), frags+MFMA on current
// LDS buffer, WRITET regs -> other buffer (per-wave vmcnt), one __syncthreads.
// LDS swizzle: chunk' = chunk ^ ((row>>1)&3), same involution on write and read.
// EPI 0 (Et): grid 640 (b%8=xcd, r=b>>3, m=r/10, n=xcd+8*(r%10), inactive return);
//   the 8 m-siblings sharing an embb 256-row panel land on one XCD's L2.
//   C[m,n]=bf16(lrelu(acc+bias[m])) for n<Nv, 0 for Nv<=n<Nw, skip n>=Nw.
// EPI 1 (fused34): grid 512 = one full round at 2 blocks/CU; group g=(which,z)
//   (16 blocks, 3.3MB unique) on XCD g%8: b = (g&7) + 8*((g>>3)*16 + j).
//   f32 plane at Cp + z*BATCH*NOUT + m*ldc + which*1024 + n.
template<int EPI>
__global__ __launch_bounds__(256, 2) void gemmQ(
    const unsigned short* __restrict__ A0p, const unsigned short* __restrict__ B0p,
    const unsigned short* __restrict__ A1p, const unsigned short* __restrict__ B1p,
    int lda, int ldb,
    const float* __restrict__ bias,
    void* __restrict__ Cp, int ldc,
    int Nv, int Nw, int K, int kChunk)
{
  __shared__ __align__(16) unsigned short AsW[2 * 128 * 32];  // 16 KB
  __shared__ __align__(16) unsigned short BsW[2 * 256 * 32];  // 32 KB

  // ---- XCD-aware decode (hardware XCD = blockIdx % 8) ----
  const int b = blockIdx.x;
  int m0, n0, z = 0, which = 0;
  if (EPI == 1) {
    int g = ((b >> 7) << 3) | (b & 7);   // 0..31, on XCD g%8
    int j = (b >> 3) & 15;               // member 0..15
    which = g >> 4; z = g & 15;
    m0 = (j & 3) * 128;
    n0 = (j >> 2) * 256;
  } else {
    int xcd = b & 7, r = b >> 3;         // r 0..79
    int m = r / 10, q = r - m * 10;
    int nidx = xcd + 8 * q;
    if (nidx >= 79) return;              // inactive pad block
    m0 = m * 128;
    n0 = nidx * 256;
  }
  const unsigned short* Ap = which ? A1p : A0p;
  const unsigned short* Bp = which ? B1p : B0p;

  const int k0   = z * kChunk;
  const int kend = min(K, k0 + kChunk);
  const int nt   = (kend - k0) >> 5;     // BK=32

  const int tid = threadIdx.x;
  const int l = tid & 63, w = tid >> 6;  // 4 waves, wave w owns n-sub w*64
  const int srow = tid >> 2;             // 0..63
  const int sc8  = tid & 3;              // 16B chunk in row
  const unsigned short* agl = Ap + (size_t)(m0 + srow) * lda + k0 + sc8 * 8;
  const unsigned short* bgl = Bp + (size_t)(n0 + srow) * ldb + k0 + sc8 * 8;
  const int swc = ((sc8 ^ ((srow >> 1) & 3)) << 3);   // swizzled LDS col (elems)

  const int lr = l & 15, lkc = l >> 4;   // frag row lane, k-chunk lane
  const int ck = ((lkc ^ ((lr >> 1) & 3)) << 3);      // swizzled read col (elems)

  f32x4 acc[8][4] = {};
  u16x8 ra0, ra1, rb0, rb1, rb2, rb3;    // named depth-1 staging (rule #20)

#define LOADT(dk)                                                           \
  do {                                                                      \
    ra0 = *reinterpret_cast<const u16x8*>(agl + (size_t)0   * lda + (dk)); \
    ra1 = *reinterpret_cast<const u16x8*>(agl + (size_t)64  * lda + (dk)); \
    rb0 = *reinterpret_cast<const u16x8*>(bgl + (size_t)0   * ldb + (dk)); \
    rb1 = *reinterpret_cast<const u16x8*>(bgl + (size_t)64  * ldb + (dk)); \
    rb2 = *reinterpret_cast<const u16x8*>(bgl + (size_t)128 * ldb + (dk)); \
    rb3 = *reinterpret_cast<const u16x8*>(bgl + (size_t)192 * ldb + (dk)); \
  } while (0)

#define WRITET(BUF)                                                         \
  do {                                                                      \
    *reinterpret_cast<u16x8*>(AsW + (BUF)*4096 + (srow      ) * 32 + swc) = ra0; \
    *reinterpret_cast<u16x8*>(AsW + (BUF)*4096 + (srow +  64) * 32 + swc) = ra1; \
    *reinterpret_cast<u16x8*>(BsW + (BUF)*8192 + (srow      ) * 32 + swc) = rb0; \
    *reinterpret_cast<u16x8*>(BsW + (BUF)*8192 + (srow +  64) * 32 + swc) = rb1; \
    *reinterpret_cast<u16x8*>(BsW + (BUF)*8192 + (srow + 128) * 32 + swc) = rb2; \
    *reinterpret_cast<u16x8*>(BsW + (BUF)*8192 + (srow + 192) * 32 + swc) = rb3; \
  } while (0)

  // ---- prologue: tile 0 -> regs -> buf 0 ----
  LOADT(0);
  WRITET(0);
  __syncthreads();

  for (int t = 0; t < nt; ++t) {
    const int buf = t & 1, nb = buf ^ 1;
    if (t + 1 < nt) LOADT((t + 1) << 5);
    __builtin_amdgcn_sched_barrier(0);   // pin the prefetch loads before compute

    bf16x8 a[8], bfr[4];
#pragma unroll
    for (int mi = 0; mi < 8; ++mi)
      a[mi] = *reinterpret_cast<const bf16x8*>(AsW + buf * 4096 + (mi * 16 + lr) * 32 + ck);
#pragma unroll
    for (int ni = 0; ni < 4; ++ni)
      bfr[ni] = *reinterpret_cast<const bf16x8*>(
          BsW + buf * 8192 + (w * 64 + ni * 16 + lr) * 32 + ck);

    __builtin_amdgcn_s_setprio(1);
#pragma unroll
    for (int mi = 0; mi < 8; ++mi)
#pragma unroll
      for (int ni = 0; ni < 4; ++ni)
        acc[mi][ni] = MFMA(a[mi], bfr[ni], acc[mi][ni]);
    __builtin_amdgcn_s_setprio(0);

    if (t + 1 < nt) WRITET(nb);          // per-wave vmcnt drains this tile's loads
    __syncthreads();                     // one barrier per K-tile
  }
#undef LOADT
#undef WRITET

  // C/D layout: col = lane&15, row = (lane>>4)*4 + reg  [m89/m91]
  const int rb_ = (l >> 4) * 4;
#pragma unroll
  for (int mi = 0; mi < 8; ++mi)
#pragma unroll
    for (int ni = 0; ni < 4; ++ni)
#pragma unroll
      for (int j = 0; j < 4; ++j) {
        int m = m0 + mi * 16 + rb_ + j;
        int n = n0 + w * 64 + ni * 16 + lr;
        float v = acc[mi][ni][j];
        if (EPI == 0) {
          if (n < Nw) {
            float t2 = v + bias[m];
            t2 = t2 > 0.f ? t2 : 0.01f * t2;
            reinterpret_cast<unsigned short*>(Cp)[(size_t)m * ldc + n] =
                (n < Nv) ? f2bf(t2) : (unsigned short)0;
          }
        } else {
          reinterpret_cast<float*>(Cp)[(size_t)z * (BATCH * NOUT) + (size_t)m * ldc +
                                       which * 1024 + n] = v;
        }
      }
}

// ===== 128x128-tile m97-style GEMM (combiner only) =====
template<int EPI>
__global__ __launch_bounds__(256) void gemm97(
    const unsigned short* __restrict__ A, const unsigned short* __restrict__ B,
    int lda, int ldb,
    const float* __restrict__ bias,
    void* __restrict__ Cp, int ldc, int pstride,
    int M, int N, int Nw, int K, int kChunk)
{
  __shared__ __align__(16) unsigned short As[128 * 64];
  __shared__ __align__(16) unsigned short Bs[128 * 64];

  const int z = blockIdx.z;
  const int m0 = blockIdx.y * 128, n0 = blockIdx.x * 128;
  const int k0   = z * kChunk;
  const int kend = min(K, k0 + kChunk);
  const int tid = threadIdx.x;
  const int l = tid & 63, w = tid >> 6;

  const int srow = w * 32 + (l >> 3);
  const int scol = (l & 7) * 8;
  const unsigned short* ag = A + (size_t)(m0 + srow) * lda + scol;
  const unsigned short* bg = B + (size_t)(n0 + srow) * ldb + scol;

  const int wm = (w >> 1) * 64, wn = (w & 1) * 64;
  const int lr = l & 15, lk = (l >> 4) * 8;

  f32x4 acc[4][4] = {};

  for (int kb = k0; kb < kend; kb += 64) {
#pragma unroll
    for (int j = 0; j < 4; ++j)
      g2l16(ag + (size_t)j * 8 * lda + kb, As + (w * 32 + j * 8) * 64);
#pragma unroll
    for (int j = 0; j < 4; ++j)
      g2l16(bg + (size_t)j * 8 * ldb + kb, Bs + (w * 32 + j * 8) * 64);
    __syncthreads();
#pragma unroll
    for (int ks = 0; ks < 2; ++ks) {
      bf16x8 a[4], b2[4];
#pragma unroll
      for (int i = 0; i < 4; ++i)
        a[i] = *reinterpret_cast<const bf16x8*>(&As[(wm + i * 16 + lr) * 64 + ks * 32 + lk]);
#pragma unroll
      for (int i = 0; i < 4; ++i)
        b2[i] = *reinterpret_cast<const bf16x8*>(&Bs[(wn + i * 16 + lr) * 64 + ks * 32 + lk]);
#pragma unroll
      for (int mi = 0; mi < 4; ++mi)
#pragma unroll
        for (int ni = 0; ni < 4; ++ni)
          acc[mi][ni] = MFMA(a[mi], b2[ni], acc[mi][ni]);
    }
    __syncthreads();
  }

  const int rb = (l >> 4) * 4;
#pragma unroll
  for (int mi = 0; mi < 4; ++mi) {
#pragma unroll
    for (int ni = 0; ni < 4; ++ni) {
#pragma unroll
      for (int j = 0; j < 4; ++j) {
        int m = m0 + wm + mi * 16 + rb + j;
        int n = n0 + wn + ni * 16 + lr;
        float v = acc[mi][ni][j];
        if (EPI == 0) {
          if (n < Nw) {
            float t = v + bias[m];
            t = t > 0.f ? t : 0.01f * t;
            reinterpret_cast<unsigned short*>(Cp)[(size_t)m * ldc + n] =
                (n < N) ? f2bf(t) : (unsigned short)0;
          }
        } else {
          reinterpret_cast<float*>(Cp)[(size_t)z * pstride + (size_t)m * ldc + n] = v;
        }
      }
    }
  }
}

// f32 [rows,cols] -> bf16 [rowsPad,colsPad], zero-filled padding. cols % 8 == 0.
__global__ __launch_bounds__(256) void convert_kernel(
    const float* __restrict__ src, unsigned short* __restrict__ dst,
    int rows, int cols, int rowsPad, int colsPad)
{
  const int cpc = colsPad >> 3;
  const int nchunks = rowsPad * cpc;
  for (int idx = blockIdx.x * 256 + threadIdx.x; idx < nchunks; idx += gridDim.x * 256) {
    int row = idx / cpc;
    int c0  = (idx - row * cpc) << 3;
    u16x8 v = {};
    if (row < rows && c0 < cols) {
      const float* p = src + (size_t)row * cols + c0;
      f32x4 f0 = *reinterpret_cast<const f32x4*>(p);
      f32x4 f1 = *reinterpret_cast<const f32x4*>(p + 4);
      v[0] = f2bf(f0[0]); v[1] = f2bf(f0[1]); v[2] = f2bf(f0[2]); v[3] = f2bf(f0[3]);
      v[4] = f2bf(f1[0]); v[5] = f2bf(f1[1]); v[6] = f2bf(f1[2]); v[7] = f2bf(f1[3]);
    }
    *reinterpret_cast<u16x8*>(dst + (size_t)row * colsPad + c0) = v;
  }
}

// Per-row softmax stats + bf16 casts: xb = bf16(x), wb = bf16(softmax(x)), stride KPAD.
__global__ __launch_bounds__(256) void prep_x_kernel(
    const float* __restrict__ x,
    unsigned short* __restrict__ xb,
    unsigned short* __restrict__ wb)
{
  const int r = blockIdx.x;
  const int t = threadIdx.x;
  const float* xr = x + (size_t)r * INPUT;

  float m = -3.4e38f, s = 0.f;
  for (int c = t; c < INPUT / 4; c += 256) {
    float4 v = reinterpret_cast<const float4*>(xr)[c];
    float cm = fmaxf(fmaxf(v.x, v.y), fmaxf(v.z, v.w));
    if (cm > m) { s *= __expf(m - cm); m = cm; }
    s += __expf(v.x - m) + __expf(v.y - m) + __expf(v.z - m) + __expf(v.w - m);
  }
#pragma unroll
  for (int off = 32; off > 0; off >>= 1) {
    float om = __shfl_xor(m, off);
    float os = __shfl_xor(s, off);
    float nm = fmaxf(m, om);
    s = s * __expf(m - nm) + os * __expf(om - nm);
    m = nm;
  }
  __shared__ float sm[4], ss[4];
  if ((t & 63) == 0) { sm[t >> 6] = m; ss[t >> 6] = s; }
  __syncthreads();
  float M4 = fmaxf(fmaxf(sm[0], sm[1]), fmaxf(sm[2], sm[3]));
  float S4 = ss[0] * __expf(sm[0] - M4) + ss[1] * __expf(sm[1] - M4)
           + ss[2] * __expf(sm[2] - M4) + ss[3] * __expf(sm[3] - M4);
  float inv = 1.f / S4;

  unsigned short* xbr = xb + (size_t)r * KPAD;
  unsigned short* wbr = wb + (size_t)r * KPAD;
  for (int c = t; c < KPAD / 4; c += 256) {
    u16x4 xo = {}, wo = {};
    if (c < INPUT / 4) {
      float4 v = reinterpret_cast<const float4*>(xr)[c];
      xo[0] = f2bf(v.x); xo[1] = f2bf(v.y); xo[2] = f2bf(v.z); xo[3] = f2bf(v.w);
      wo[0] = f2bf(__expf(v.x - M4) * inv);
      wo[1] = f2bf(__expf(v.y - M4) * inv);
      wo[2] = f2bf(__expf(v.z - M4) * inv);
      wo[3] = f2bf(__expf(v.w - M4) * inv);
    }
    reinterpret_cast<u16x4*>(xbr)[c] = xo;
    reinterpret_cast<u16x4*>(wbr)[c] = wo;
  }
}

// Sum S split-K planes; MODE 0: combined buffer (b_ge+lrelu on cols<1024 only, bf16 out)
//                       MODE 1: final output (b_c+lrelu on all cols, f32 out)
template<int S, int MODE>
__global__ __launch_bounds__(256) void reduce_kernel(
    const float* __restrict__ P, const float* __restrict__ bias, void* __restrict__ outp)
{
  size_t base = ((size_t)blockIdx.x * 256 + threadIdx.x) * 4;
  f32x4 s = {};
#pragma unroll
  for (int zz = 0; zz < S; ++zz)
    s += *reinterpret_cast<const f32x4*>(P + (size_t)zz * BATCH * NOUT + base);
  int n = (int)(base & (NOUT - 1));
  if (MODE == 0) {
    u16x4 o;
    if (n < 1024) {
#pragma unroll
      for (int j = 0; j < 4; ++j) {
        float v = s[j] + bias[n + j];
        v = v > 0.f ? v : 0.01f * v;
        o[j] = f2bf(v);
      }
    } else {
#pragma unroll
      for (int j = 0; j < 4; ++j) o[j] = f2bf(s[j]);
    }
    *reinterpret_cast<u16x4*>(reinterpret_cast<unsigned short*>(outp) + base) = o;
  } else {
    f32x4 o;
#pragma unroll
    for (int j = 0; j < 4; ++j) {
      float v = s[j] + bias[n + j];
      o[j] = v > 0.f ? v : 0.01f * v;
    }
    *reinterpret_cast<f32x4*>(reinterpret_cast<float*>(outp) + base) = o;
  }
}

extern "C" void kernel_launch(void* const* d_in, const int* in_sizes, int n_in,
                              void* d_out, int out_size, void* d_ws, size_t ws_size,
                              hipStream_t stream)
{
  const float* x    = (const float*)d_in[0];
  const float* emb  = (const float*)d_in[1];
  const float* W_ge = (const float*)d_in[2];
  const float* b_ge = (const float*)d_in[3];
  const float* W_em = (const float*)d_in[4];
  const float* b_em = (const float*)d_in[5];
  const float* W_c  = (const float*)d_in[6];
  const float* b_c  = (const float*)d_in[7];
  float* out = (float*)d_out;

  char* ws = (char*)d_ws;
  unsigned short* xb   = (unsigned short*)(ws);                      // 512x20032 bf16  = 20,512,768
  unsigned short* wb   = (unsigned short*)(ws + 20512768);           // 20,512,768
  unsigned short* Wgeb = (unsigned short*)(ws + 41025536);           // 1024x20032 bf16 = 41,025,536
  unsigned short* Et   = (unsigned short*)(ws + 82051072);           // 1024x20032 bf16 = 41,025,536
  unsigned short* Wcb  = (unsigned short*)(ws + 123076608);          // 2048x2048 bf16  =  8,388,608
  unsigned short* comb = (unsigned short*)(ws + 131465216);          // 512x2048 bf16   =  2,097,152
  float*          P    = (float*)(ws + 133562368);                   // 16x512x2048 f32 = 67,108,864
  // embb/Wemb alias the P region (dead before P is first written)
  unsigned short* embb = (unsigned short*)(ws + 133562368);          // 20224x512 bf16  = 20,709,376
  unsigned short* Wemb = (unsigned short*)(ws + 133562368 + 20709376); // 1024x512 bf16 =  1,048,576
  // total ws usage: ~200.7 MB

  // 1) bf16 conversions (zero-padded)
  convert_kernel<<<1024, 256, 0, stream>>>(emb,  embb, INPUT, EMBED, NPADE, EMBED);
  convert_kernel<<<256,  256, 0, stream>>>(W_em, Wemb, HIDDEN, EMBED, HIDDEN, EMBED);
  convert_kernel<<<1024, 256, 0, stream>>>(W_ge, Wgeb, HIDDEN, INPUT, HIDDEN, KPAD);
  convert_kernel<<<512,  256, 0, stream>>>(W_c,  Wcb,  NOUT, NOUT, NOUT, NOUT);

  // 2) softmax stats + bf16 casts of x (stride KPAD, zero tail)
  prep_x_kernel<<<BATCH, 256, 0, stream>>>(x, xb, wb);

  // 3) Et[h,g] = lrelu(W_em @ emb^T + b_em): M=1024, N=20000 (pad 20032), K=512
  //    640-block grid (632 active), 2 blocks/CU, embb-panel m-siblings per XCD.
  gemmQ<0><<<640, 256, 0, stream>>>(
      Wemb, embb, nullptr, nullptr, EMBED, EMBED, b_em,
      Et, KPAD, INPUT, KPAD, EMBED, EMBED);

  // 4) fused split-K partials: which=0: xb @ Wgeb^T -> cols 0..1023
  //                            which=1: wb @ Et^T   -> cols 1024..2047
  //    512 blocks = one full round at 2 blocks/CU; (which,z) groups per XCD.
  gemmQ<1><<<512, 256, 0, stream>>>(
      xb, Wgeb, wb, Et, KPAD, KPAD, nullptr,
      P, NOUT, 0, 0, KPAD, 1280);

  // 5) reduce 16 planes -> combined bf16 [512, 2048] (+b_ge+lrelu on first half)
  reduce_kernel<16, 0><<<(BATCH * NOUT / 4) / 256, 256, 0, stream>>>(P, b_ge, comb);

  // 6) combiner partials: comb @ Wcb^T (M=512, N=2048, K=2048, S=4)
  gemm97<1><<<dim3(16, 4, 4), 256, 0, stream>>>(
      comb, Wcb, NOUT, NOUT, nullptr,
      P, NOUT, BATCH * NOUT, BATCH, NOUT, NOUT, NOUT, 512);

  // 7) reduce 4 planes + b_c + lrelu -> f32 out [512, 2048]
  reduce_kernel<4, 1><<<(BATCH * NOUT / 4) / 256, 256, 0, stream>>>(P, b_c, out);
}